// Round 10
// baseline (95.035 us; speedup 1.0000x reference)
//
#include <hip/hip_runtime.h>
#include <math.h>

#define NB 16
#define NA 5
#define NH 96
#define NW 96
#define TT 50
#define HW (NH*NW)        // 9216
#define APB (NA*HW)       // 46080 cells per batch
#define CPT 4             // cells per thread — empirical optimum (R2..R9 sweep)
#define CPB (256*CPT)     // 1024 cells per block

__device__ __constant__ float c_aw[NA] = {1.3221f, 3.19275f, 5.05587f, 9.47112f, 11.2364f};
__device__ __constant__ float c_ah[NA] = {1.73145f, 4.00944f, 8.09892f, 4.84053f, 10.0071f};

__device__ __forceinline__ float sigmoidf(float x) { return 1.0f / (1.0f + __expf(-x)); }

// Two-kernel structure (stream-ordered, so prep completes before loss starts):
//  prep  : per batch, computes hot GT records -> global (for loss's s_load loop),
//          and for each WINNER cell computes the full assigned-cell loss MINUS a
//          bit-exact replica of the noobj term loss_kernel will add there.
//  loss  : pure noobj pass — no LDS data path, no barrier, no map, no branch.
// hot record (8 floats/t): gxl,gxr,gyl,gyr,g06n(-0.6*garea | -1e30),0,0,0
__global__ void prep_kernel(const float* __restrict__ target,
                            const float* __restrict__ outp,
                            float* __restrict__ ghot,
                            float* __restrict__ out) {
    int b = blockIdx.x;
    int t = threadIdx.x;            // 64 threads = one wave
    __shared__ float s_hot[TT*8];
    __shared__ int   s_cell[TT];

    float xraw = (t < TT) ? target[(b*TT + t)*6 + 1] : 1.0f;
    unsigned long long m = __ballot(xraw != 0.0f);

    int valid = 0, best = 0, cell = -1, gi = 0, gj = 0;
    float gx=0, gy=0, gw=1, gh=1, tcls=0, lr=0;
    if (t < TT) {
        valid = (((~m) & ((2ull << t) - 1ull)) == 0ull) ? 1 : 0;
        const float* tg = target + (b*TT + t)*6;
        tcls = tg[0];
        gx = tg[1]*NW; gy = tg[2]*NH; gw = tg[3]*NW; gh = tg[4]*NH;
        lr = tg[5];
        float bi = -1.0f;
        for (int a2 = 0; a2 < NA; ++a2) {
            float inter = fminf(gw, c_aw[a2]) * fminf(gh, c_ah[a2]);
            float iou = inter / (gw*gh + c_aw[a2]*c_ah[a2] - inter);
            if (iou > bi) { bi = iou; best = a2; }
        }
        gi = (int)gx; gj = (int)gy;
        cell = valid ? (best*HW + gj*NW + gi) : -1;
        s_cell[t] = cell;
        float* rh = &s_hot[t*8];
        if (valid) {
            rh[0] = gx - 0.5f*gw; rh[1] = gx + 0.5f*gw;
            rh[2] = gy - 0.5f*gh; rh[3] = gy + 0.5f*gh;
            rh[4] = -0.6f*gw*gh;
        } else {
            rh[0] = 0.0f; rh[1] = 0.0f; rh[2] = 0.0f; rh[3] = 0.0f;
            rh[4] = -1e30f;
        }
        rh[5] = 0.0f; rh[6] = 0.0f; rh[7] = 0.0f;
        // publish hot records for the loss kernel's scalar-load loop
        float4* gdst = (float4*)(ghot + (b*TT + t)*8);
        gdst[0] = *(const float4*)&rh[0];
        gdst[1] = *(const float4*)&rh[4];
    }
    __syncthreads();

    float acc = 0.0f;
    if (t < TT && valid) {
        // winner = last valid t mapping to this cell (scan scatter = last-write-wins)
        int winner = 1;
        for (int u = t + 1; u < TT; ++u)
            if (s_cell[u] == cell) { winner = 0; break; }
        if (winner) {
            int a = best;
            int rem = gj*NW + gi;
            const float* base = outp + (size_t)((b*NA + a)*8)*HW + rem;
            float o0 = base[0*HW], o1 = base[1*HW], o2 = base[2*HW], o3 = base[3*HW];
            float o4 = base[4*HW], o5 = base[5*HW], o6 = base[6*HW], o7 = base[7*HW];
            float sx = sigmoidf(o0), sy = sigmoidf(o1);
            float px = sx + (float)gi, py = sy + (float)gj;
            float pw = __expf(o2) * c_aw[a];
            float ph = __expf(o3) * c_ah[a];
            float pxl = px - 0.5f*pw, pxr = px + 0.5f*pw;
            float pyl = py - 0.5f*ph, pyr = py + 0.5f*ph;
            float parea = pw*ph;
            // ---- bit-exact replica of loss_kernel's noobj computation ----
            float maxv = -1e30f;
            for (int u = 0; u < TT; ++u) {
                const float* rh = &s_hot[u*8];
                float cw = fminf(pxr, rh[1]) - fmaxf(pxl, rh[0]);
                float ch = fminf(pyr, rh[3]) - fmaxf(pyl, rh[2]);
                float carea = fmaxf(cw, 0.0f) * ch;       // one-clamp form, as in loss
                maxv = fmaxf(maxv, fmaf(1.6f, carea, rh[4]));
            }
            float conf = sigmoidf(o4);
            float noobj = (maxv > 0.6f*parea) ? 0.0f : 0.5f*conf*conf;
            // ---- assigned-cell loss (exact two-clamp IoU) ----
            float gxl = gx - 0.5f*gw, gxr = gx + 0.5f*gw;
            float gyl = gy - 0.5f*gh, gyr = gy + 0.5f*gh;
            float cw = fminf(pxr, gxr) - fmaxf(pxl, gxl);
            float ch = fminf(pyr, gyr) - fmaxf(pyl, gyl);
            float carea = fmaxf(cw, 0.0f) * fmaxf(ch, 0.0f);
            float tconf = carea / (parea + gw*gh - carea);
            float dc = conf - tconf;
            acc = 2.5f*dc*dc;                             // 0.5 * OBJECT_SCALE
            float tx = gx - (float)gi, ty = gy - (float)gj;
            float tw = logf(gw / c_aw[best]), th = logf(gh / c_ah[best]);
            float dx = sx - tx, dy = sy - ty, dw = o2 - tw, dh = o3 - th;
            acc += 0.5f*(dx*dx + dy*dy + dw*dw + dh*dh);
            float mm  = fmaxf(o5, o6);
            float lse = mm + __logf(__expf(o5 - mm) + __expf(o6 - mm));
            acc += lse - ((tcls != 0.0f) ? o6 : o5);      // 2-class CE
            float dl = sigmoidf(o7) - lr;
            acc += 0.25f*dl*dl;                           // 0.5 * mse_half(conf_lr)
            acc -= noobj;                                 // loss_kernel adds it back
        }
    }
    for (int off = 32; off > 0; off >>= 1) acc += __shfl_down(acc, off, 64);
    if (t == 0) atomicAdd(out, acc * (1.0f/NB));
}

// Pure noobj kernel: no LDS data path, no prologue barrier, no assigned branch.
// GT records are block-uniform -> compiler scalarizes to s_load (SGPR operands
// are free in VALU ops).
__global__ __launch_bounds__(256)
void loss_kernel(const float* __restrict__ outp,
                 const float* __restrict__ ghot,
                 float* __restrict__ loss) {
    __shared__ float s_sum[4];
    int b   = blockIdx.y;
    int tid = threadIdx.x;
    int cell0 = blockIdx.x*CPB + tid*CPT;
    int a   = cell0 / HW;                  // 1024 | 9216: blocks never straddle an anchor
    int rem = cell0 - a*HW;
    int j   = rem / NW;
    int i0  = rem - j*NW;                  // 4 | 96: quads never straddle a row

    const float* base = outp + (size_t)((b*NA + a)*8)*HW + rem;
    float4 v0 = *(const float4*)(base + 0*HW);
    float4 v1 = *(const float4*)(base + 1*HW);
    float4 v2 = *(const float4*)(base + 2*HW);
    float4 v3 = *(const float4*)(base + 3*HW);
    float4 v4 = *(const float4*)(base + 4*HW);
    float o0[CPT] = {v0.x, v0.y, v0.z, v0.w};
    float o1[CPT] = {v1.x, v1.y, v1.z, v1.w};
    float o2[CPT] = {v2.x, v2.y, v2.z, v2.w};
    float o3[CPT] = {v3.x, v3.y, v3.z, v3.w};
    float o4[CPT] = {v4.x, v4.y, v4.z, v4.w};

    float aw = c_aw[a], ah = c_ah[a];
    float pxl[CPT], pxr[CPT], pyl[CPT], pyr[CPT], p6[CPT], maxv[CPT];
    #pragma unroll
    for (int c = 0; c < CPT; ++c) {
        float sx = sigmoidf(o0[c]), sy = sigmoidf(o1[c]);
        float px = sx + (float)(i0 + c);
        float py = sy + (float)j;
        float pw = __expf(o2[c]) * aw;
        float ph = __expf(o3[c]) * ah;
        pxl[c] = px - 0.5f*pw; pxr[c] = px + 0.5f*pw;
        pyl[c] = py - 0.5f*ph; pyr[c] = py + 0.5f*ph;
        p6[c]  = 0.6f*(pw*ph);
        maxv[c] = -1e30f;
    }

    // GT loop: block-uniform scalar loads, 10 VALU/pair (one-clamp form —
    // if ch<0 the product <=0 so 1.6*carea+g06n < 0 < p6: decision unchanged).
    const float* g = ghot + b*(TT*8);
    #pragma unroll 10
    for (int t = 0; t < TT; ++t) {
        const float* r = g + t*8;
        float gxl = r[0], gxr = r[1], gyl = r[2], gyr = r[3], g06n = r[4];
        #pragma unroll
        for (int c = 0; c < CPT; ++c) {
            float cw = fminf(pxr[c], gxr) - fmaxf(pxl[c], gxl);
            float ch = fminf(pyr[c], gyr) - fmaxf(pyl[c], gyl);
            float carea = fmaxf(cw, 0.0f) * ch;
            maxv[c] = fmaxf(maxv[c], fmaf(1.6f, carea, g06n));
        }
    }

    float acc = 0.0f;
    #pragma unroll
    for (int c = 0; c < CPT; ++c) {
        float conf = sigmoidf(o4[c]);
        acc += (maxv[c] > p6[c]) ? 0.0f : 0.5f*conf*conf;
    }

    for (int off = 32; off > 0; off >>= 1) acc += __shfl_down(acc, off, 64);
    int lane = tid & 63, wid = tid >> 6;
    if (lane == 0) s_sum[wid] = acc;
    __syncthreads();
    if (tid == 0) {
        float s = (s_sum[0] + s_sum[1]) + (s_sum[2] + s_sum[3]);
        atomicAdd(loss, s * (1.0f/NB));
    }
}

extern "C" void kernel_launch(void* const* d_in, const int* in_sizes, int n_in,
                              void* d_out, int out_size, void* d_ws, size_t ws_size,
                              hipStream_t stream) {
    const float* output = (const float*)d_in[0];
    const float* target = (const float*)d_in[1];
    float* ghot = (float*)d_ws;                 // NB*TT*8 floats = 25.6 KB
    float* out  = (float*)d_out;

    hipMemsetAsync(out, 0, (size_t)out_size*sizeof(float), stream);
    hipLaunchKernelGGL(prep_kernel, dim3(NB), dim3(64), 0, stream,
                       target, output, ghot, out);
    dim3 grid(APB/CPB, NB);                     // 45 x 16 = 720 blocks
    hipLaunchKernelGGL(loss_kernel, grid, dim3(256), 0, stream,
                       output, ghot, out);
}